// Round 2
// baseline (1125.935 us; speedup 1.0000x reference)
//
#include <hip/hip_runtime.h>

#define H       4096
#define RANK    16
#define NROWS   16384      // BATCH * SEQ
#define RPB     4          // rows per block
#define TPB     256
#define TWO_OVER_PI 0.63661977236758134f

typedef float f32x4 __attribute__((ext_vector_type(4)));
typedef float f32x2 __attribute__((ext_vector_type(2)));

// ---- prep: repack int32-stored int8 A/B into BIASED uint8 (v+128) ----
// A layout: word i = col (i>>2), ranks (i&3)*4..+3 -> int4 per column.
// B layout permuted so phase-2 thread t loads one int4 per rank:
//   out word o: c=o&3, t=(o>>2)&255, r=o>>10  <- in word r*1024 + c*256 + t
__global__ __launch_bounds__(256) void pack_ab(const int* __restrict__ A32,
                                               const int* __restrict__ B32,
                                               unsigned int* __restrict__ A8,
                                               unsigned int* __restrict__ B8) {
    int i = blockIdx.x * 256 + threadIdx.x;      // 0..16383
    int4 a = ((const int4*)A32)[i];
    A8[i] = ((unsigned)((a.x + 128) & 0xff))       | ((unsigned)((a.y + 128) & 0xff) << 8) |
            ((unsigned)((a.z + 128) & 0xff) << 16) | ((unsigned)((a.w + 128) & 0xff) << 24);

    int c = i & 3, tt = (i >> 2) & 255, r = i >> 10;
    int4 b = ((const int4*)B32)[r * 1024 + c * 256 + tt];
    B8[i] = ((unsigned)((b.x + 128) & 0xff))       | ((unsigned)((b.y + 128) & 0xff) << 8) |
            ((unsigned)((b.z + 128) & 0xff) << 16) | ((unsigned)((b.w + 128) & 0xff) << 24);
}

// ---- fused: h = x@A, out = x + 2*sin((h@B)*sB*2/pi) ----
// RPB=4, row-paired float2 accumulators -> v_pk_fma_f32 (2x fp32 rate).
// x is consumed in register chunks in phase 1 and re-read (L2/L3 hit) in the
// epilogue; no x in LDS -> LDS ~1.3 KB, occupancy VGPR-bound at 4 waves/SIMD.
__global__ __launch_bounds__(TPB, 4) void pilora_fused(
    const float* __restrict__ x,
    const unsigned int* __restrict__ A8,    // biased uint8, int4 per column
    const unsigned int* __restrict__ B8,    // permuted, biased uint8
    const float* __restrict__ sA,           // [16]
    const float* __restrict__ sB,           // [H]
    float* __restrict__ out)
{
    const int t    = threadIdx.x;
    const int lane = t & 63;
    const int wid  = t >> 6;
    const int row0 = blockIdx.x * RPB;

    __shared__ float wsum[4][64];                                // per-wave partials
    __shared__ __attribute__((aligned(16))) float hsh[64];       // h[r][rr] at r*4+rr (scaled by sA)
    __shared__ float HsLds[RPB];                                 // 128 * sum_r h[rr][r]

    const f32x4* x4 = (const f32x4*)x;

    // ---- phase 1: per-thread partial h over this thread's 16 columns ----
    // row-pairs packed: w01[r] = {row0, row1}, w23[r] = {row2, row3}
    f32x2 w01[16], w23[16];
    #pragma unroll
    for (int j = 0; j < 16; ++j) { w01[j] = (f32x2)0.0f; w23[j] = (f32x2)0.0f; }
    f32x2 sx01 = (f32x2)0.0f, sx23 = (f32x2)0.0f;

    const int4* A16 = (const int4*)A8;
    #pragma unroll
    for (int c = 0; c < 4; ++c) {
        f32x4 xv0 = x4[(row0 + 0) * 1024 + c * 256 + t];
        f32x4 xv1 = x4[(row0 + 1) * 1024 + c * 256 + t];
        f32x4 xv2 = x4[(row0 + 2) * 1024 + c * 256 + t];
        f32x4 xv3 = x4[(row0 + 3) * 1024 + c * 256 + t];
        #pragma unroll
        for (int e = 0; e < 4; ++e) {
            int4 q = A16[c * 1024 + t * 4 + e];
            f32x2 x01; x01[0] = xv0[e]; x01[1] = xv1[e];
            f32x2 x23; x23[0] = xv2[e]; x23[1] = xv3[e];
            sx01 += x01; sx23 += x23;
            int qw[4] = {q.x, q.y, q.z, q.w};
            #pragma unroll
            for (int wi = 0; wi < 4; ++wi) {
                unsigned uw = (unsigned)qw[wi];
                #pragma unroll
                for (int b = 0; b < 4; ++b) {
                    float u = (float)((uw >> (8 * b)) & 0xffu);   // v_cvt_f32_ubyteN
                    f32x2 u2; u2[0] = u; u2[1] = u;
                    w01[wi * 4 + b] += x01 * u2;                  // v_pk_fma_f32
                    w23[wi * 4 + b] += x23 * u2;
                }
            }
        }
    }
    #pragma unroll
    for (int j = 0; j < 16; ++j) {
        w01[j] -= sx01 * 128.0f;
        w23[j] -= sx23 * 128.0f;
    }

    // ---- flatten to value index v = rr*16 + r (all compile-time indices) ----
    float wf[64];
    #pragma unroll
    for (int r = 0; r < 16; ++r) {
        wf[ 0 + r] = w01[r][0];
        wf[16 + r] = w01[r][1];
        wf[32 + r] = w23[r][0];
        wf[48 + r] = w23[r][1];
    }

    // ---- in-wave butterfly: 64 values over 64 lanes; lane ends with v=lane ----
    #pragma unroll
    for (int b = 0; b < 6; ++b) {
        int q = (lane >> b) & 1;
        #pragma unroll
        for (int k = 0; k < (32 >> b); ++k) {
            float keep = q ? wf[2 * k + 1] : wf[2 * k];
            float send = q ? wf[2 * k]     : wf[2 * k + 1];
            wf[k] = keep + __shfl_xor(send, 1 << b, 64);
        }
    }
    wsum[wid][lane] = wf[0];
    __syncthreads();

    // ---- cross-wave combine + scale; Hs[rr] = 128 * sum_r h[rr][r] ----
    if (t < 64) {
        float v = wsum[0][t] + wsum[1][t] + wsum[2][t] + wsum[3][t];
        int r = t & 15, rr = t >> 4;
        float hv = v * sA[r];
        hsh[r * 4 + rr] = hv;
        float hs = hv;
        hs += __shfl_xor(hs, 1, 64);
        hs += __shfl_xor(hs, 2, 64);
        hs += __shfl_xor(hs, 4, 64);
        hs += __shfl_xor(hs, 8, 64);
        if (r == 0) HsLds[rr] = 128.0f * hs;
    }
    __syncthreads();

    // ---- phase 2: g[rr][j] = sum_r h[rr][r]*(u-128), row-paired pk_fma ----
    f32x2 nh01, nh23;
    nh01[0] = -HsLds[0]; nh01[1] = -HsLds[1];
    nh23[0] = -HsLds[2]; nh23[1] = -HsLds[3];

    f32x2 g01[16], g23[16];
    #pragma unroll
    for (int j = 0; j < 16; ++j) { g01[j] = nh01; g23[j] = nh23; }

    const int4* Bp = (const int4*)B8;
    #pragma unroll 4
    for (int r = 0; r < RANK; ++r) {
        f32x4 hr = *(const f32x4*)&hsh[r * 4];
        f32x2 h01; h01[0] = hr[0]; h01[1] = hr[1];
        f32x2 h23; h23[0] = hr[2]; h23[1] = hr[3];
        int4 bw = Bp[r * 256 + t];
        int bwa[4] = {bw.x, bw.y, bw.z, bw.w};
        #pragma unroll
        for (int wi = 0; wi < 4; ++wi) {
            unsigned uw = (unsigned)bwa[wi];
            #pragma unroll
            for (int b = 0; b < 4; ++b) {
                float u = (float)((uw >> (8 * b)) & 0xffu);
                f32x2 u2; u2[0] = u; u2[1] = u;
                g01[wi * 4 + b] += h01 * u2;                     // v_pk_fma_f32
                g23[wi * 4 + b] += h23 * u2;
            }
        }
    }

    // ---- epilogue: out = x + 2*sin(g*sB*2/pi); x re-read (L2/L3 hit) ----
    const f32x4* sB4 = (const f32x4*)sB;
    f32x4* o4 = (f32x4*)out;
    #pragma unroll
    for (int c = 0; c < 4; ++c) {
        f32x4 sb  = sB4[c * 256 + t];
        f32x4 xv0 = x4[(row0 + 0) * 1024 + c * 256 + t];
        f32x4 xv1 = x4[(row0 + 1) * 1024 + c * 256 + t];
        f32x4 xv2 = x4[(row0 + 2) * 1024 + c * 256 + t];
        f32x4 xv3 = x4[(row0 + 3) * 1024 + c * 256 + t];
        f32x4 o0, o1, o2, o3;
        #pragma unroll
        for (int b = 0; b < 4; ++b) {
            float k = sb[b] * TWO_OVER_PI;
            o0[b] = xv0[b] + 2.0f * __sinf(g01[c * 4 + b][0] * k);
            o1[b] = xv1[b] + 2.0f * __sinf(g01[c * 4 + b][1] * k);
            o2[b] = xv2[b] + 2.0f * __sinf(g23[c * 4 + b][0] * k);
            o3[b] = xv3[b] + 2.0f * __sinf(g23[c * 4 + b][1] * k);
        }
        __builtin_nontemporal_store(o0, &o4[(row0 + 0) * 1024 + c * 256 + t]);
        __builtin_nontemporal_store(o1, &o4[(row0 + 1) * 1024 + c * 256 + t]);
        __builtin_nontemporal_store(o2, &o4[(row0 + 2) * 1024 + c * 256 + t]);
        __builtin_nontemporal_store(o3, &o4[(row0 + 3) * 1024 + c * 256 + t]);
    }
}

extern "C" void kernel_launch(void* const* d_in, const int* in_sizes, int n_in,
                              void* d_out, int out_size, void* d_ws, size_t ws_size,
                              hipStream_t stream) {
    const float* x   = (const float*)d_in[0];
    const int*   A32 = (const int*)d_in[1];
    const int*   B32 = (const int*)d_in[2];
    const float* sA  = (const float*)d_in[3];
    const float* sB  = (const float*)d_in[4];
    float*       out = (float*)d_out;

    unsigned int* A8 = (unsigned int*)d_ws;               // 64 KB
    unsigned int* B8 = A8 + (H * RANK / 4);               // 64 KB

    pack_ab<<<(H * RANK / 4) / 256, 256, 0, stream>>>(A32, B32, A8, B8);
    pilora_fused<<<NROWS / RPB, TPB, 0, stream>>>(
        x, A8, B8, sA, sB, out);
}

// Round 3
// 624.496 us; speedup vs baseline: 1.8029x; 1.8029x over previous
//
#include <hip/hip_runtime.h>

#define H       4096
#define RANK    16
#define NROWS   16384      // BATCH * SEQ
#define RPB     2          // rows per block
#define TPB     256
#define TWO_OVER_PI 0.63661977236758134f

typedef float f32x4 __attribute__((ext_vector_type(4)));
typedef float f32x2 __attribute__((ext_vector_type(2)));

// ---- prep: repack int32-stored int8 A/B into BIASED uint8 (v+128) ----
// A layout: word i = col (i>>2), ranks (i&3)*4..+3 -> int4 per column.
// B layout permuted so phase-2 thread t loads one int4 per rank:
//   out word o: c=o&3, t=(o>>2)&255, r=o>>10  <- in word r*1024 + c*256 + t
__global__ __launch_bounds__(256) void pack_ab(const int* __restrict__ A32,
                                               const int* __restrict__ B32,
                                               unsigned int* __restrict__ A8,
                                               unsigned int* __restrict__ B8) {
    int i = blockIdx.x * 256 + threadIdx.x;      // 0..16383
    int4 a = ((const int4*)A32)[i];
    A8[i] = ((unsigned)((a.x + 128) & 0xff))       | ((unsigned)((a.y + 128) & 0xff) << 8) |
            ((unsigned)((a.z + 128) & 0xff) << 16) | ((unsigned)((a.w + 128) & 0xff) << 24);

    int c = i & 3, tt = (i >> 2) & 255, r = i >> 10;
    int4 b = ((const int4*)B32)[r * 1024 + c * 256 + tt];
    B8[i] = ((unsigned)((b.x + 128) & 0xff))       | ((unsigned)((b.y + 128) & 0xff) << 8) |
            ((unsigned)((b.z + 128) & 0xff) << 16) | ((unsigned)((b.w + 128) & 0xff) << 24);
}

// ---- fused: h = x@A, out = x + 2*sin((h@B)*sB*2/pi) ----
// RPB=2, row-paired f32x2 accumulators -> v_pk_fma_f32 (2x fp32 rate).
// x read global->reg in phase 1, re-read from L2 in epilogue; LDS ~1 KB.
// waves_per_eu(6,6): 84-VGPR budget, 6 waves/SIMD — blocks the R2 failure
// where the allocator spilled ~2.3 GB of scratch chasing 8 waves/SIMD.
__global__ __launch_bounds__(TPB)
__attribute__((amdgpu_waves_per_eu(6, 6)))
void pilora_fused(
    const float* __restrict__ x,
    const unsigned int* __restrict__ A8,    // biased uint8, int4 per column
    const unsigned int* __restrict__ B8,    // permuted, biased uint8
    const float* __restrict__ sA,           // [16]
    const float* __restrict__ sB,           // [H]
    float* __restrict__ out)
{
    const int t    = threadIdx.x;
    const int lane = t & 63;
    const int wid  = t >> 6;
    const int row0 = blockIdx.x * RPB;

    __shared__ float wsum[4][32];                                // per-wave partials
    __shared__ __attribute__((aligned(8))) float hsh[32];        // h[r][rr] at r*2+rr (scaled by sA)
    __shared__ float HsLds[RPB];                                 // 128 * sum_r h[rr][r]

    const f32x4* x4 = (const f32x4*)x;

    // ---- phase 1: per-thread partial h over this thread's 16 columns ----
    // w01[r] = {row0 partial, row1 partial}; biased (u = a+128), corrected after.
    f32x2 w01[16];
    #pragma unroll
    for (int j = 0; j < 16; ++j) w01[j] = (f32x2)0.0f;
    f32x2 sx01 = (f32x2)0.0f;

    const int4* A16 = (const int4*)A8;
    #pragma unroll
    for (int c = 0; c < 4; ++c) {
        f32x4 xv0 = x4[(row0 + 0) * 1024 + c * 256 + t];
        f32x4 xv1 = x4[(row0 + 1) * 1024 + c * 256 + t];
        #pragma unroll
        for (int e = 0; e < 4; ++e) {
            int4 q = A16[c * 1024 + t * 4 + e];
            f32x2 x01; x01[0] = xv0[e]; x01[1] = xv1[e];
            sx01 += x01;
            int qw[4] = {q.x, q.y, q.z, q.w};
            #pragma unroll
            for (int wi = 0; wi < 4; ++wi) {
                unsigned uw = (unsigned)qw[wi];
                #pragma unroll
                for (int b = 0; b < 4; ++b) {
                    float u = (float)((uw >> (8 * b)) & 0xffu);   // v_cvt_f32_ubyteN
                    f32x2 u2; u2[0] = u; u2[1] = u;
                    w01[wi * 4 + b] += x01 * u2;                  // v_pk_fma_f32
                }
            }
        }
    }
    #pragma unroll
    for (int j = 0; j < 16; ++j) w01[j] -= sx01 * 128.0f;

    // ---- in-wave butterfly: 32 values (v = rr*16 + r) over 64 lanes ----
    // stage 0 fused over w01 (no 32-wide flatten; keeps peak pressure low):
    // val(v) = w01[v & 15][v >> 4]
    float wf[16];
    #pragma unroll
    for (int k = 0; k < 16; ++k) {
        float va = w01[(2 * k) & 15][(2 * k) >> 4];
        float vb = w01[(2 * k + 1) & 15][(2 * k + 1) >> 4];
        float keep = (lane & 1) ? vb : va;
        float send = (lane & 1) ? va : vb;
        wf[k] = keep + __shfl_xor(send, 1, 64);
    }
    #pragma unroll
    for (int b = 1; b < 5; ++b) {
        int q = (lane >> b) & 1;
        #pragma unroll
        for (int k = 0; k < (16 >> b); ++k) {
            float keep = q ? wf[2 * k + 1] : wf[2 * k];
            float send = q ? wf[2 * k]     : wf[2 * k + 1];
            wf[k] = keep + __shfl_xor(send, 1 << b, 64);
        }
    }
    wf[0] += __shfl_xor(wf[0], 32, 64);   // lane holds full-wave sum of v = lane&31

    if (lane < 32) wsum[wid][lane] = wf[0];
    __syncthreads();

    // ---- cross-wave combine + scale; Hs[rr] = 128 * sum_r h[rr][r] ----
    if (t < 32) {
        float v = wsum[0][t] + wsum[1][t] + wsum[2][t] + wsum[3][t];
        int r = t & 15, rr = t >> 4;
        float hv = v * sA[r];
        hsh[r * 2 + rr] = hv;
        float hs = hv;
        hs += __shfl_xor(hs, 1, 64);
        hs += __shfl_xor(hs, 2, 64);
        hs += __shfl_xor(hs, 4, 64);
        hs += __shfl_xor(hs, 8, 64);
        if (r == 0) HsLds[rr] = 128.0f * hs;
    }
    __syncthreads();

    // ---- phase 2: g[rr][j] = sum_r h[rr][r]*(u-128), row-paired pk_fma ----
    f32x2 nh; nh[0] = -HsLds[0]; nh[1] = -HsLds[1];

    f32x2 g01[16];
    #pragma unroll
    for (int j = 0; j < 16; ++j) g01[j] = nh;

    const int4* Bp = (const int4*)B8;
    #pragma unroll 4
    for (int r = 0; r < RANK; ++r) {
        f32x2 h01 = *(const f32x2*)&hsh[r * 2];
        int4 bw = Bp[r * 256 + t];
        int bwa[4] = {bw.x, bw.y, bw.z, bw.w};
        #pragma unroll
        for (int wi = 0; wi < 4; ++wi) {
            unsigned uw = (unsigned)bwa[wi];
            #pragma unroll
            for (int b = 0; b < 4; ++b) {
                float u = (float)((uw >> (8 * b)) & 0xffu);
                f32x2 u2; u2[0] = u; u2[1] = u;
                g01[wi * 4 + b] += h01 * u2;                     // v_pk_fma_f32
            }
        }
    }

    // ---- epilogue: out = x + 2*sin(g*sB*2/pi); x re-read (L2 hit) ----
    const f32x4* sB4 = (const f32x4*)sB;
    f32x4* o4 = (f32x4*)out;
    #pragma unroll
    for (int c = 0; c < 4; ++c) {
        f32x4 sb  = sB4[c * 256 + t];
        f32x4 xv0 = x4[(row0 + 0) * 1024 + c * 256 + t];
        f32x4 xv1 = x4[(row0 + 1) * 1024 + c * 256 + t];
        f32x4 o0, o1;
        #pragma unroll
        for (int b = 0; b < 4; ++b) {
            float k = sb[b] * TWO_OVER_PI;
            o0[b] = xv0[b] + 2.0f * __sinf(g01[c * 4 + b][0] * k);
            o1[b] = xv1[b] + 2.0f * __sinf(g01[c * 4 + b][1] * k);
        }
        __builtin_nontemporal_store(o0, &o4[(row0 + 0) * 1024 + c * 256 + t]);
        __builtin_nontemporal_store(o1, &o4[(row0 + 1) * 1024 + c * 256 + t]);
    }
}

extern "C" void kernel_launch(void* const* d_in, const int* in_sizes, int n_in,
                              void* d_out, int out_size, void* d_ws, size_t ws_size,
                              hipStream_t stream) {
    const float* x   = (const float*)d_in[0];
    const int*   A32 = (const int*)d_in[1];
    const int*   B32 = (const int*)d_in[2];
    const float* sA  = (const float*)d_in[3];
    const float* sB  = (const float*)d_in[4];
    float*       out = (float*)d_out;

    unsigned int* A8 = (unsigned int*)d_ws;               // 64 KB
    unsigned int* B8 = A8 + (H * RANK / 4);               // 64 KB

    pack_ab<<<(H * RANK / 4) / 256, 256, 0, stream>>>(A32, B32, A8, B8);
    pilora_fused<<<NROWS / RPB, TPB, 0, stream>>>(
        x, A8, B8, sA, sB, out);
}

// Round 4
// 550.676 us; speedup vs baseline: 2.0446x; 1.1341x over previous
//
#include <hip/hip_runtime.h>

#define H       4096
#define RANK    16
#define NROWS   16384      // BATCH * SEQ
#define RPB     16         // rows per block (16x16x32 MFMA M-dim)
#define TPB     256
#define TWO_OVER_PI 0.63661977236758134f

typedef float f32x4  __attribute__((ext_vector_type(4)));
typedef short bf16x8 __attribute__((ext_vector_type(8)));
typedef unsigned int u32;

union Pack8 { u32 w[4]; bf16x8 v; };

// ---- prep: int32-stored int8 -> exact bf16 (int8 fits bf16 exactly) ----
// At [16][4096]  = A^T   (phase-1 B-operand: lane reads 8 consecutive k)
// Bt [4096][16]  = B^T   (phase-2 A-operand: lane reads 8 consecutive ranks)
__global__ __launch_bounds__(256) void pack_ab(const int* __restrict__ A32,
                                               const int* __restrict__ B32,
                                               unsigned short* __restrict__ At,
                                               unsigned short* __restrict__ Bt) {
    int i = blockIdx.x * 256 + threadIdx.x;          // 0..65535
    {   // At[r][k] = bf16(A32[k][r]); i = r*4096 + k
        int r = i >> 12, k = i & 4095;
        float f = (float)A32[k * RANK + r];
        At[i] = (unsigned short)(__float_as_uint(f) >> 16);   // exact for |v|<=127
    }
    {   // Bt[c][r] = bf16(B32[r][c]); i = c*16 + r
        int c = i >> 4, r = i & 15;
        float f = (float)B32[r * H + c];
        Bt[i] = (unsigned short)(__float_as_uint(f) >> 16);
    }
}

// ---- fused MFMA kernel ----
// Phase 1: h[16r][16rk] = x @ A   (K=4096 split across 4 waves, x as bf16 hi+lo)
// Phase 2: g = h @ B, swapped operands so C-frag -> f32x4 row-major stores;
//          h_hi packed in k0..15, h_lo in k16..31 (B duplicated via addressing).
__global__ __launch_bounds__(TPB, 4) void pilora_fused(
    const float* __restrict__ x,
    const unsigned short* __restrict__ At,   // [16][4096] bf16
    const unsigned short* __restrict__ Bt,   // [4096][16] bf16
    const float* __restrict__ sA,            // [16]
    const float* __restrict__ sB,            // [H]
    float* __restrict__ out)
{
    const int t    = threadIdx.x;
    const int lane = t & 63;
    const int wid  = t >> 6;
    const int row0 = blockIdx.x * RPB;
    const int m16  = lane & 15;              // A-op row / C-frag n-index
    const int kg   = lane >> 4;              // k-group 0..3 (8 k each)

    __shared__ float ph[4][16][16];          // per-wave partial h tiles
    __shared__ float h_lds[16][16];          // reduced h, scaled by sA

    // ================= phase 1: partial h via MFMA =================
    // A-op: lane holds x[row0+m16][k0 + kg*8 + i]  (i=0..7, f32 -> bf16 hi/lo)
    // B-op: lane holds A[k0+kg*8+i][rank m16] = At[m16][k0+kg*8+i]
    f32x4 acc = {0.f, 0.f, 0.f, 0.f};
    {
        const float*          xbase = x  + (size_t)(row0 + m16) * H + wid * 1024 + kg * 8;
        const unsigned short* abase = At + m16 * H                  + wid * 1024 + kg * 8;
        #pragma unroll 4
        for (int kk = 0; kk < 32; ++kk) {
            f32x4 xa = *(const f32x4*)(xbase + kk * 32);
            f32x4 xb = *(const f32x4*)(xbase + kk * 32 + 4);
            bf16x8 af = *(const bf16x8*)(abase + kk * 32);
            float xe[8] = {xa[0], xa[1], xa[2], xa[3], xb[0], xb[1], xb[2], xb[3]};
            Pack8 hi, lo;
            #pragma unroll
            for (int p = 0; p < 4; ++p) {
                u32 b0 = __float_as_uint(xe[2 * p]);
                u32 b1 = __float_as_uint(xe[2 * p + 1]);
                hi.w[p] = (b1 & 0xFFFF0000u) | (b0 >> 16);
                float l0 = xe[2 * p]     - __uint_as_float(b0 & 0xFFFF0000u);  // exact
                float l1 = xe[2 * p + 1] - __uint_as_float(b1 & 0xFFFF0000u);
                lo.w[p] = (__float_as_uint(l1) & 0xFFFF0000u) | (__float_as_uint(l0) >> 16);
            }
            acc = __builtin_amdgcn_mfma_f32_16x16x32_bf16(hi.v, af, acc, 0, 0, 0);
            acc = __builtin_amdgcn_mfma_f32_16x16x32_bf16(lo.v, af, acc, 0, 0, 0);
        }
    }
    // C-frag: lane holds h_part[row = kg*4+reg][rank = m16]
    #pragma unroll
    for (int reg = 0; reg < 4; ++reg)
        ph[wid][kg * 4 + reg][m16] = acc[reg];
    __syncthreads();

    // cross-wave reduce + sA scale (256 threads: one (row, rank) each)
    {
        int rr = t >> 4, rk = t & 15;
        float s = ph[0][rr][rk] + ph[1][rr][rk] + ph[2][rr][rk] + ph[3][rr][rk];
        h_lds[rr][rk] = s * sA[rk];
    }
    __syncthreads();

    // ================= phase 2: g = h @ B, fused epilogue =================
    // B-op (h): lane l -> n = m16 (x-row), k = kg*8+i;
    //   k<16 -> h_hi[n][k], k>=16 -> h_lo[n][k-16]   (Dekker split of h)
    Pack8 hf;
    {
        const float* hp = &h_lds[m16][(kg & 1) * 8];
        const bool lohalf = (lane >= 32);
        #pragma unroll
        for (int p = 0; p < 4; ++p) {
            float e0 = hp[2 * p], e1 = hp[2 * p + 1];
            u32 b0 = __float_as_uint(e0), b1 = __float_as_uint(e1);
            if (lohalf) {
                float l0 = e0 - __uint_as_float(b0 & 0xFFFF0000u);
                float l1 = e1 - __uint_as_float(b1 & 0xFFFF0000u);
                b0 = __float_as_uint(l0); b1 = __float_as_uint(l1);
            }
            hf.w[p] = (b1 & 0xFFFF0000u) | (b0 >> 16);
        }
    }

    // A-op (B^T): lane l -> m = m16 (col offset), k = kg*8+i;
    //   value = B[k mod 16][cb+m] = Bt[cb+m][k mod 16]  (dup across K halves)
    const int colw = wid * 1024;
    const int row  = row0 + m16;
    #pragma unroll 2
    for (int j = 0; j < 64; ++j) {
        int cb = colw + j * 16;
        bf16x8 bfrag = *(const bf16x8*)(Bt + (cb + m16) * RANK + (kg & 1) * 8);
        f32x4 z = {0.f, 0.f, 0.f, 0.f};
        f32x4 g = __builtin_amdgcn_mfma_f32_16x16x32_bf16(bfrag, hf.v, z, 0, 0, 0);
        // C-frag: lane holds g[row = m16][col = cb + kg*4 + reg] -> f32x4 store
        int col = cb + kg * 4;
        f32x4 sb = *(const f32x4*)(sB + col);
        f32x4 xv = *(const f32x4*)(x + (size_t)row * H + col);
        f32x4 o;
        #pragma unroll
        for (int e = 0; e < 4; ++e)
            o[e] = xv[e] + 2.0f * __sinf(g[e] * (sb[e] * TWO_OVER_PI));
        *(f32x4*)(out + (size_t)row * H + col) = o;
    }
}

extern "C" void kernel_launch(void* const* d_in, const int* in_sizes, int n_in,
                              void* d_out, int out_size, void* d_ws, size_t ws_size,
                              hipStream_t stream) {
    const float* x   = (const float*)d_in[0];
    const int*   A32 = (const int*)d_in[1];
    const int*   B32 = (const int*)d_in[2];
    const float* sA  = (const float*)d_in[3];
    const float* sB  = (const float*)d_in[4];
    float*       out = (float*)d_out;

    unsigned short* At = (unsigned short*)d_ws;          // 128 KB
    unsigned short* Bt = At + (size_t)RANK * H;          // 128 KB

    pack_ab<<<(RANK * H) / 256, 256, 0, stream>>>(A32, B32, At, Bt);
    pilora_fused<<<NROWS / RPB, TPB, 0, stream>>>(x, At, Bt, sA, sB, out);
}

// Round 5
// 504.017 us; speedup vs baseline: 2.2339x; 1.0926x over previous
//
#include <hip/hip_runtime.h>

#define H       4096
#define RANK    16
#define NROWS   16384      // BATCH * SEQ
#define RPB     16         // rows per block (16x16x32 MFMA M-dim)
#define TPB     512        // 8 waves: K and column space split 8 ways
#define WPB     8
#define TWO_OVER_PI 0.63661977236758134f

typedef float f32x4  __attribute__((ext_vector_type(4)));
typedef short bf16x8 __attribute__((ext_vector_type(8)));
typedef unsigned int u32;

union Pack8 { u32 w[4]; bf16x8 v; };

// ---- prep: int32-stored int8 -> exact bf16 (int8 fits bf16 exactly) ----
// At [16][4096]  = A^T   (phase-1 B-operand: lane reads 8 consecutive k)
// Bt [4096][16]  = B^T   (phase-2 A-operand: lane reads 8 consecutive ranks)
__global__ __launch_bounds__(256) void pack_ab(const int* __restrict__ A32,
                                               const int* __restrict__ B32,
                                               unsigned short* __restrict__ At,
                                               unsigned short* __restrict__ Bt) {
    int i = blockIdx.x * 256 + threadIdx.x;          // 0..65535
    {   // At[r][k] = bf16(A32[k][r]); i = r*4096 + k
        int r = i >> 12, k = i & 4095;
        float f = (float)A32[k * RANK + r];
        At[i] = (unsigned short)(__float_as_uint(f) >> 16);   // exact for |v|<=127
    }
    {   // Bt[c][r] = bf16(B32[r][c]); i = c*16 + r
        int c = i >> 4, r = i & 15;
        float f = (float)B32[r * H + c];
        Bt[i] = (unsigned short)(__float_as_uint(f) >> 16);
    }
}

// ---- fused MFMA kernel ----
// Phase 1: h[16r][16rk] = x @ A   (K=4096 split across 8 waves, x as bf16 hi+lo)
// Phase 2: g = h @ B, swapped operands so C-frag -> f32x4 row-major stores;
//          h_hi packed in k0..15, h_lo in k16..31 (B duplicated via addressing).
// TPB=512: 4 blocks/CU x 8 waves = 32 waves/CU (100% occupancy cap) --
// R4 at TPB=256 was grid-starved (16 waves/CU cap, 38% measured).
__global__ __launch_bounds__(TPB) void pilora_fused(
    const float* __restrict__ x,
    const unsigned short* __restrict__ At,   // [16][4096] bf16
    const unsigned short* __restrict__ Bt,   // [4096][16] bf16
    const float* __restrict__ sA,            // [16]
    const float* __restrict__ sB,            // [H]
    float* __restrict__ out)
{
    const int t    = threadIdx.x;
    const int lane = t & 63;
    const int wid  = t >> 6;                 // 0..7
    const int row0 = blockIdx.x * RPB;
    const int m16  = lane & 15;              // A-op row / C-frag n-index
    const int kg   = lane >> 4;              // k-group 0..3 (8 k each)

    __shared__ float ph[WPB][16][16];        // per-wave partial h tiles (8 KB)
    __shared__ float h_lds[16][16];          // reduced h, scaled by sA

    // ================= phase 1: partial h via MFMA =================
    // wave wid covers K segment [wid*512, wid*512+512)
    f32x4 acc = {0.f, 0.f, 0.f, 0.f};
    {
        const float*          xbase = x  + (size_t)(row0 + m16) * H + wid * 512 + kg * 8;
        const unsigned short* abase = At + m16 * H                  + wid * 512 + kg * 8;
        #pragma unroll 4
        for (int kk = 0; kk < 16; ++kk) {
            f32x4 xa = *(const f32x4*)(xbase + kk * 32);
            f32x4 xb = *(const f32x4*)(xbase + kk * 32 + 4);
            bf16x8 af = *(const bf16x8*)(abase + kk * 32);
            float xe[8] = {xa[0], xa[1], xa[2], xa[3], xb[0], xb[1], xb[2], xb[3]};
            Pack8 hi, lo;
            #pragma unroll
            for (int p = 0; p < 4; ++p) {
                u32 b0 = __float_as_uint(xe[2 * p]);
                u32 b1 = __float_as_uint(xe[2 * p + 1]);
                hi.w[p] = (b1 & 0xFFFF0000u) | (b0 >> 16);
                float l0 = xe[2 * p]     - __uint_as_float(b0 & 0xFFFF0000u);  // exact
                float l1 = xe[2 * p + 1] - __uint_as_float(b1 & 0xFFFF0000u);
                lo.w[p] = (__float_as_uint(l1) & 0xFFFF0000u) | (__float_as_uint(l0) >> 16);
            }
            acc = __builtin_amdgcn_mfma_f32_16x16x32_bf16(hi.v, af, acc, 0, 0, 0);
            acc = __builtin_amdgcn_mfma_f32_16x16x32_bf16(lo.v, af, acc, 0, 0, 0);
        }
    }
    // C-frag: lane holds h_part[row = kg*4+reg][rank = m16]
    #pragma unroll
    for (int reg = 0; reg < 4; ++reg)
        ph[wid][kg * 4 + reg][m16] = acc[reg];
    __syncthreads();

    // cross-wave reduce + sA scale (first 256 threads: one (row, rank) each)
    if (t < 256) {
        int rr = t >> 4, rk = t & 15;
        float s = 0.f;
        #pragma unroll
        for (int w = 0; w < WPB; ++w) s += ph[w][rr][rk];
        h_lds[rr][rk] = s * sA[rk];
    }
    __syncthreads();

    // ================= phase 2: g = h @ B, fused epilogue =================
    // B-op (h): lane l -> n = m16 (x-row), k = kg*8+i;
    //   k<16 -> h_hi[n][k], k>=16 -> h_lo[n][k-16]   (Dekker split of h)
    Pack8 hf;
    {
        const float* hp = &h_lds[m16][(kg & 1) * 8];
        const bool lohalf = (lane >= 32);
        #pragma unroll
        for (int p = 0; p < 4; ++p) {
            float e0 = hp[2 * p], e1 = hp[2 * p + 1];
            u32 b0 = __float_as_uint(e0), b1 = __float_as_uint(e1);
            if (lohalf) {
                float l0 = e0 - __uint_as_float(b0 & 0xFFFF0000u);
                float l1 = e1 - __uint_as_float(b1 & 0xFFFF0000u);
                b0 = __float_as_uint(l0); b1 = __float_as_uint(l1);
            }
            hf.w[p] = (b1 & 0xFFFF0000u) | (b0 >> 16);
        }
    }

    // A-op (B^T): lane l -> m = m16 (col offset), k = kg*8+i;
    //   value = B[k mod 16][cb+m] = Bt[cb+m][k mod 16]  (dup across K halves)
    // wave wid covers columns [wid*512, wid*512+512) -> 32 col-tiles
    const int colw = wid * 512;
    const int row  = row0 + m16;
    #pragma unroll 2
    for (int j = 0; j < 32; ++j) {
        int cb = colw + j * 16;
        bf16x8 bfrag = *(const bf16x8*)(Bt + (cb + m16) * RANK + (kg & 1) * 8);
        f32x4 z = {0.f, 0.f, 0.f, 0.f};
        f32x4 g = __builtin_amdgcn_mfma_f32_16x16x32_bf16(bfrag, hf.v, z, 0, 0, 0);
        // C-frag: lane holds g[row = m16][col = cb + kg*4 + reg] -> f32x4 store
        int col = cb + kg * 4;
        f32x4 sb = *(const f32x4*)(sB + col);
        f32x4 xv = *(const f32x4*)(x + (size_t)row * H + col);
        f32x4 o;
        #pragma unroll
        for (int e = 0; e < 4; ++e)
            o[e] = xv[e] + 2.0f * __sinf(g[e] * (sb[e] * TWO_OVER_PI));
        *(f32x4*)(out + (size_t)row * H + col) = o;
    }
}

extern "C" void kernel_launch(void* const* d_in, const int* in_sizes, int n_in,
                              void* d_out, int out_size, void* d_ws, size_t ws_size,
                              hipStream_t stream) {
    const float* x   = (const float*)d_in[0];
    const int*   A32 = (const int*)d_in[1];
    const int*   B32 = (const int*)d_in[2];
    const float* sA  = (const float*)d_in[3];
    const float* sB  = (const float*)d_in[4];
    float*       out = (float*)d_out;

    unsigned short* At = (unsigned short*)d_ws;          // 128 KB
    unsigned short* Bt = At + (size_t)RANK * H;          // 128 KB

    pack_ab<<<(RANK * H) / 256, 256, 0, stream>>>(A32, B32, At, Bt);
    pilora_fused<<<NROWS / RPB, TPB, 0, stream>>>(x, At, Bt, sA, sB, out);
}